// Round 15
// baseline (320.676 us; speedup 1.0000x reference)
//
#include <hip/hip_runtime.h>

#define NN 50000
#define HID 128
#define HH (HID * HID)
#define NE 800000
#define ET (NE + NN)          // edges + self loops
#define NEG_SLOPE 0.2f
#define CAP 64                // padded CSR slots per node (max deg ~45)
#define WTOT (3 * HID * HID)  // 49152
#define VTOT (3 * 3 * HID)    // 1152
#define SCHUNK 1024
#define SCAT_BLKS ((ET + SCHUNK - 1) / SCHUNK)   // 831 (de-replicated: 1 block/chunk)
#define GEMM_VB ((NN + 63) / 64)                 // 782
#define AG_VB ((NN + 31) / 32)                   // 1563: 32-row tiles for fused agg+gemm
#define WL3 (3 * HH)          // per-layer Wb stride: [swz-hi][plain-lo][plain-hi]

typedef __attribute__((ext_vector_type(8))) short short8v;  // 8 bf16 = 4 VGPRs
typedef __attribute__((ext_vector_type(4))) float f32x4;    // MFMA accumulator

__device__ inline float b2f(unsigned short u) {
    union { unsigned int i; float f; } x; x.i = ((unsigned int)u) << 16; return x.f;
}
__device__ inline float f_lo(unsigned int u) {
    union { unsigned int i; float f; } x; x.i = u << 16; return x.f;
}
__device__ inline float f_hi(unsigned int u) {
    union { unsigned int i; float f; } x; x.i = u & 0xFFFF0000u; return x.f;
}
__device__ inline unsigned short f2b(float f) {
    unsigned int x; __builtin_memcpy(&x, &f, 4);
    unsigned int lsb = (x >> 16) & 1u;
    x += 0x7fffu + lsb;                  // round-to-nearest-even
    return (unsigned short)(x >> 16);
}
__device__ inline void splitbf(float v, unsigned short& hi, unsigned short& lo) {
    hi = f2b(v);
    lo = f2b(v - b2f(hi));
}
__device__ inline float readlane_f(float v, int l) {
    union { float f; int i; } x; x.f = v;
    x.i = __builtin_amdgcn_readlane(x.i, l);
    return x.f;
}
// block-local dtype probe (128 even-halfword samples of z); includes a barrier
__device__ __forceinline__ int probe_hf_dev(const unsigned short* z, int t, int* sflag) {
    if (t < 64) {
        unsigned short a = z[t * 4];
        unsigned short b = z[t * 4 + 2];
        int ea = (a >> 7) & 0xFF, eb = (b >> 7) & 0xFF;
        int w1 = (ea >= 0x9A || (ea <= 0x30 && a != 0)) ? 1 : 0;
        int w2 = (eb >= 0x9A || (eb <= 0x30 && b != 0)) ? 1 : 0;
        int wild = __popcll(__ballot(w1)) + __popcll(__ballot(w2));
        if (t == 0) *sflag = (wild < 8) ? 1 : 0;
    }
    __syncthreads();
    return *sflag;
}

// ---------- prep: dtype + W three forms + param vectors + pos zero ----------
__global__ __launch_bounds__(256) void prep(
        const unsigned short* __restrict__ z, const void* __restrict__ Ws,
        const void* __restrict__ as_, const void* __restrict__ ad_,
        const void* __restrict__ b_, unsigned short* __restrict__ Wb,
        float* __restrict__ asf, float* __restrict__ adf, float* __restrict__ bff,
        int* __restrict__ pos) {
    __shared__ int sflag;
    const int t = threadIdx.x;
    const int f = probe_hf_dev(z, t, &sflag);
    const int gtid = blockIdx.x * 256 + t;
    if (gtid < NN) pos[gtid] = 0;
    if (gtid < WTOT) {
        // per layer: [swz-hi 32KB LDS image][plain-lo W^T][plain-hi W^T], k contig
        int L = gtid >> 14, k = (gtid >> 7) & 127, n = gtid & 127;
        float v = f ? b2f(((const unsigned short*)Ws)[gtid]) : ((const float*)Ws)[gtid];
        unsigned short hi, lo;
        splitbf(v, hi, lo);
        unsigned short* hbase = Wb + (size_t)L * WL3;
        int bo = (n * 256 + k * 2) ^ ((n & 7) << 4);
        *(unsigned short*)((char*)hbase + bo) = hi;     // swizzled hi (LDS image)
        hbase[HH + n * HID + k]     = lo;               // plain lo
        hbase[2 * HH + n * HID + k] = hi;               // plain hi
    } else {
        int i = gtid - WTOT;
        if (i < VTOT) {
            int which = i / (3 * HID), j = i - which * (3 * HID);
            const void* in = which == 0 ? as_ : which == 1 ? ad_ : b_;
            float* o = which == 0 ? asf : which == 1 ? adf : bff;
            o[j] = f ? b2f(((const unsigned short*)in)[j]) : ((const float*)in)[j];
        }
    }
}

// ---------- merged gemm layer 0 (FIRST in grid) + CSR scatter (after) ----------
__global__ __launch_bounds__(256) void scat_gemm0(
        const unsigned short* __restrict__ z, const int* __restrict__ ei,
        const unsigned short* __restrict__ Wb, const float* __restrict__ a_s,
        const float* __restrict__ a_d, int* __restrict__ pos, int* __restrict__ csr,
        unsigned short* __restrict__ x, float* __restrict__ als, float* __restrict__ ald) {
    __shared__ unsigned short Wh[HH];   // 32 KB swizzled W-hi image
    __shared__ int sflag;
    const int t = threadIdx.x;

    if (blockIdx.x >= GEMM_VB) {        // ---- scatter branch (block-uniform) ----
        const int base = (blockIdx.x - GEMM_VB) * SCHUNK;
#pragma unroll
        for (int k = 0; k < SCHUNK / 256; ++k) {
            int e = base + k * 256 + t;
            if (e >= ET) continue;
            int d = (e < NE) ? ei[NE + e] : (e - NE);
            int s = (e < NE) ? ei[e] : d;
            int slot = atomicAdd(&pos[d], 1);
            if (slot < CAP) csr[(d << 6) + slot] = s;
        }
        return;
    }

    // ---- gemm layer 0 branch ----
    const int hf = probe_hf_dev(z, t, &sflag);
    const int base = blockIdx.x * 64;
    const unsigned short* Wlo = Wb + HH;
#pragma unroll
    for (int i = 0; i < 8; ++i) {
        int c = i * 256 + t;
        ((short8v*)Wh)[c] = ((const short8v*)Wb)[c];
    }
    __syncthreads();

    const int w  = t >> 6;
    const int l  = t & 63;
    const int lr = l & 15;
    const int lk = l >> 4;
    const int arow = base + w * 16 + lr;
    const bool rowok = (arow < NN);

    const short8v zv = (short8v){0, 0, 0, 0, 0, 0, 0, 0};
    short8v ahi[4], alo[4];
    if (hf) {
        const unsigned short* hp = z + (size_t)arow * HID + lk * 8;
#pragma unroll
        for (int ks = 0; ks < 4; ++ks) {
            ahi[ks] = rowok ? *(const short8v*)(hp + ks * 32) : zv;
            alo[ks] = zv;
        }
    } else {
        const float* hp = (const float*)z + (size_t)arow * HID + lk * 8;
#pragma unroll
        for (int ks = 0; ks < 4; ++ks) {
            float4 v0 = make_float4(0.f, 0.f, 0.f, 0.f), v1 = v0;
            if (rowok) {
                v0 = *(const float4*)(hp + ks * 32);
                v1 = *(const float4*)(hp + ks * 32 + 4);
            }
            ushort4 h0, l0, h1, l1;
            splitbf(v0.x, h0.x, l0.x); splitbf(v0.y, h0.y, l0.y);
            splitbf(v0.z, h0.z, l0.z); splitbf(v0.w, h0.w, l0.w);
            splitbf(v1.x, h1.x, l1.x); splitbf(v1.y, h1.y, l1.y);
            splitbf(v1.z, h1.z, l1.z); splitbf(v1.w, h1.w, l1.w);
            ahi[ks] = (short8v){(short)h0.x, (short)h0.y, (short)h0.z, (short)h0.w,
                                (short)h1.x, (short)h1.y, (short)h1.z, (short)h1.w};
            alo[ks] = (short8v){(short)l0.x, (short)l0.y, (short)l0.z, (short)l0.w,
                                (short)l1.x, (short)l1.y, (short)l1.z, (short)l1.w};
        }
    }

    f32x4 acc[8];
#pragma unroll
    for (int nt = 0; nt < 8; ++nt) acc[nt] = (f32x4){0.f, 0.f, 0.f, 0.f};

#pragma unroll
    for (int ks = 0; ks < 4; ++ks) {
#pragma unroll
        for (int nt = 0; nt < 8; ++nt) {
            int row = nt * 16 + lr;
            int bo = (row * 256 + ks * 64 + lk * 16) ^ ((lr & 7) << 4);
            short8v bhi = *(const short8v*)((const char*)Wh + bo);
            short8v blo = *(const short8v*)(Wlo + row * HID + ks * 32 + lk * 8);
            acc[nt] = __builtin_amdgcn_mfma_f32_16x16x32_bf16(ahi[ks], bhi, acc[nt], 0, 0, 0);
            if (!hf) acc[nt] = __builtin_amdgcn_mfma_f32_16x16x32_bf16(alo[ks], bhi, acc[nt], 0, 0, 0);
            acc[nt] = __builtin_amdgcn_mfma_f32_16x16x32_bf16(ahi[ks], blo, acc[nt], 0, 0, 0);
        }
    }

    float ps[4] = {0.f, 0.f, 0.f, 0.f};
    float pd[4] = {0.f, 0.f, 0.f, 0.f};
#pragma unroll
    for (int nt = 0; nt < 8; ++nt) {
        float asv = a_s[nt * 16 + lr];
        float adv = a_d[nt * 16 + lr];
#pragma unroll
        for (int r = 0; r < 4; ++r) {
            ps[r] = fmaf(acc[nt][r], asv, ps[r]);
            pd[r] = fmaf(acc[nt][r], adv, pd[r]);
        }
    }
#pragma unroll
    for (int m = 8; m >= 1; m >>= 1) {
#pragma unroll
        for (int r = 0; r < 4; ++r) {
            ps[r] += __shfl_xor(ps[r], m, 16);
            pd[r] += __shfl_xor(pd[r], m, 16);
        }
    }
#pragma unroll
    for (int r = 0; r < 4; ++r) {
        int grow = base + w * 16 + lk * 4 + r;
        if (grow < NN) {
#pragma unroll
            for (int nt = 0; nt < 8; ++nt)
                x[(size_t)grow * HID + nt * 16 + lr] = f2b(acc[nt][r]);
            if (lr == 0) { als[grow] = ps[r]; ald[grow] = pd[r]; }
        }
    }
}

// ---------- fused aggregate(L) + gemm(L+1), v4: dual-edge 8-B gathers ----------
// R13 base (serial 4 nodes/wave) with phase-2 widened: lane covers 4 cols
// (li = lane&31), wave halves split an edge PAIR (half = lane>>5) -> one 8-B
// load serves 2 edges; rounds/node halve (Poisson(17) deg: ~1.5 -> ~1.0) and
// requests become 512 B/wave. Cross-half combine = shfl_xor(32) at the end
// (fp32 re-association only; edge order is already nondeterministic).
// launch_bounds(512,4): VGPR cap 128 so u[16] stays in flight (R13/R14
// compiled at 32-36 VGPR -> loads were batch-serialized).
__global__ __launch_bounds__(512, 4) void agg_gemm(
        const unsigned short* __restrict__ xin, const int* __restrict__ deg_,
        const int* __restrict__ csr, const float* __restrict__ als_in,
        const float* __restrict__ ald_in, const float* __restrict__ bias,
        const unsigned short* __restrict__ Whip, const unsigned short* __restrict__ Wlop,
        const float* __restrict__ a_s, const float* __restrict__ a_d,
        unsigned short* __restrict__ xout, float* __restrict__ als_out,
        float* __restrict__ ald_out) {
    __shared__ unsigned short Ah[32 * HID];   // 8 KB h-hi, swizzled
    __shared__ unsigned short Al[32 * HID];   // 8 KB h-lo, swizzled
    __shared__ float aps[32][4], apd[32][4];  // cross-wc alpha partials (1 KB)
    const int t = threadIdx.x;
    const int base = blockIdx.x * 32;
    const int w = t >> 6;                     // 8 waves
    const int lane = t & 63;
    const int li = lane & 31;                 // col group: 4 cols
    const int half = lane >> 5;               // 0: even edge, 1: odd edge
    const unsigned int* x2 = (const unsigned int*)xin;
    const float4 bv4 = ((const float4*)bias)[li];

    // ---- agg phase: 4 nodes per wave (serial), dual-edge gathers ----
    for (int i = 0; i < 4; ++i) {
        const int r = w * 4 + i;                     // tile row 0..31
        const int node = base + r;
        const int deg = (node < NN) ? min(deg_[node], CAP) : 0;
        int   sidx = 0;
        float p    = 0.f;
        if (lane < deg) {
            sidx = csr[(node << 6) + lane];
            float e = als_in[sidx] + ald_in[node];
            e = fmaxf(e, NEG_SLOPE * e);             // leaky_relu
            e = fminf(e, 60.f);                      // inf hardening
            p = __expf(e);
        }
        float den = p;
#pragma unroll
        for (int m = 1; m < 64; m <<= 1) den += __shfl_xor(den, m);
        p *= 1.f / (den + 1e-16f);                   // 0 on padding lanes

        float a4[4] = {0.f, 0.f, 0.f, 0.f};
#pragma unroll
        for (int j0 = 0; j0 < CAP; j0 += 32) {
            if (j0 >= deg) break;                    // wave-uniform group skip
            unsigned long long u[16]; float pj[16];
#pragma unroll
            for (int k = 0; k < 16; ++k) {
                const int je = j0 + 2 * k;           // uniform lane indices
                int ia = __builtin_amdgcn_readlane(sidx, je);
                int ib = __builtin_amdgcn_readlane(sidx, je + 1);
                float pa = readlane_f(p, je);
                float pb = readlane_f(p, je + 1);
                int isel = half ? ib : ia;
                pj[k] = half ? pb : pa;              // 0 beyond deg
                const unsigned long long* rowp =
                    (const unsigned long long*)(x2 + (((size_t)(unsigned)isel) << 6));
                u[k] = rowp[li];                     // 8 B: 4 bf16 cols
            }
#pragma unroll
            for (int k = 0; k < 16; ++k) {
                unsigned int lo32 = (unsigned int)u[k];
                unsigned int hi32 = (unsigned int)(u[k] >> 32);
                a4[0] = fmaf(pj[k], f_lo(lo32), a4[0]);
                a4[1] = fmaf(pj[k], f_hi(lo32), a4[1]);
                a4[2] = fmaf(pj[k], f_lo(hi32), a4[2]);
                a4[3] = fmaf(pj[k], f_hi(hi32), a4[3]);
            }
        }
#pragma unroll
        for (int c = 0; c < 4; ++c) a4[c] += __shfl_xor(a4[c], 32);  // even+odd halves

        // bias + relu + split-bf16 into swizzled LDS (half 0 writes 8 B)
        float o0 = fmaxf(a4[0] + bv4.x, 0.f);
        float o1 = fmaxf(a4[1] + bv4.y, 0.f);
        float o2 = fmaxf(a4[2] + bv4.z, 0.f);
        float o3 = fmaxf(a4[3] + bv4.w, 0.f);
        if (half == 0) {
            ushort4 ph, pl;
            splitbf(o0, ph.x, pl.x); splitbf(o1, ph.y, pl.y);
            splitbf(o2, ph.z, pl.z); splitbf(o3, ph.w, pl.w);
            const int bo = (r * 256 + li * 8) ^ ((r & 7) << 4);   // 8-B aligned
            *(ushort4*)((char*)Ah + bo) = ph;
            *(ushort4*)((char*)Al + bo) = pl;
        }
    }
    __syncthreads();    // all h rows visible to all waves

    // ---- gemm phase: wave (wr,wc) = 16 rows x 32 cols; A LDS, B global ----
    const int wr = w & 1;
    const int wc = w >> 1;        // 0..3
    const int lr = lane & 15;
    const int lk = lane >> 4;
    const int ar = wr * 16 + lr;
    short8v ahi[4], alo[4];
#pragma unroll
    for (int ks = 0; ks < 4; ++ks) {
        int ab = (ar * 256 + ks * 64 + lk * 16) ^ ((ar & 7) << 4);
        ahi[ks] = *(const short8v*)((const char*)Ah + ab);
        alo[ks] = *(const short8v*)((const char*)Al + ab);
    }

    f32x4 acc[2];
#pragma unroll
    for (int nt = 0; nt < 2; ++nt) acc[nt] = (f32x4){0.f, 0.f, 0.f, 0.f};

#pragma unroll
    for (int ks = 0; ks < 4; ++ks) {
#pragma unroll
        for (int nt = 0; nt < 2; ++nt) {
            int row = wc * 32 + nt * 16 + lr;
            short8v bhi = *(const short8v*)(Whip + row * HID + ks * 32 + lk * 8);
            short8v blo = *(const short8v*)(Wlop + row * HID + ks * 32 + lk * 8);
            acc[nt] = __builtin_amdgcn_mfma_f32_16x16x32_bf16(ahi[ks], bhi, acc[nt], 0, 0, 0);
            acc[nt] = __builtin_amdgcn_mfma_f32_16x16x32_bf16(alo[ks], bhi, acc[nt], 0, 0, 0);
            acc[nt] = __builtin_amdgcn_mfma_f32_16x16x32_bf16(ahi[ks], blo, acc[nt], 0, 0, 0);
        }
    }

    // ---- epilogue: alpha partials (this wave's 32 cols) + 4-way wc combine ----
    float ps[4] = {0.f, 0.f, 0.f, 0.f};
    float pd[4] = {0.f, 0.f, 0.f, 0.f};
#pragma unroll
    for (int nt = 0; nt < 2; ++nt) {
        float asv = a_s[wc * 32 + nt * 16 + lr];
        float adv = a_d[wc * 32 + nt * 16 + lr];
#pragma unroll
        for (int r = 0; r < 4; ++r) {
            ps[r] = fmaf(acc[nt][r], asv, ps[r]);
            pd[r] = fmaf(acc[nt][r], adv, pd[r]);
        }
    }
#pragma unroll
    for (int m = 8; m >= 1; m >>= 1) {
#pragma unroll
        for (int r = 0; r < 4; ++r) {
            ps[r] += __shfl_xor(ps[r], m, 16);
            pd[r] += __shfl_xor(pd[r], m, 16);
        }
    }
    if (lr == 0) {
#pragma unroll
        for (int r = 0; r < 4; ++r) {
            int rib = wr * 16 + lk * 4 + r;
            aps[rib][wc] = ps[r];
            apd[rib][wc] = pd[r];
        }
    }
    __syncthreads();

#pragma unroll
    for (int r = 0; r < 4; ++r) {
        int rib = wr * 16 + lk * 4 + r;
        int grow = base + rib;
        if (grow < NN) {
#pragma unroll
            for (int nt = 0; nt < 2; ++nt)
                xout[(size_t)grow * HID + wc * 32 + nt * 16 + lr] = f2b(acc[nt][r]);
            if (wc == 0 && lr == 0) {
                als_out[grow] = (aps[rib][0] + aps[rib][1]) + (aps[rib][2] + aps[rib][3]);
                ald_out[grow] = (apd[rib][0] + apd[rib][1]) + (apd[rib][2] + apd[rib][3]);
            }
        }
    }
}

// ---------- final aggregate (layer 2, no relu) -> d_out, dual-edge gathers ----------
__global__ __launch_bounds__(256) void agg_fin(
        const unsigned short* __restrict__ z, const unsigned short* __restrict__ x,
        const int* __restrict__ deg_, const int* __restrict__ csr,
        const float* __restrict__ als, const float* __restrict__ ald,
        const float* __restrict__ bias, void* __restrict__ out) {
    __shared__ int sflag;
    const int t = threadIdx.x;
    const int hf = probe_hf_dev(z, t, &sflag);
    const int node = (blockIdx.x * 256 + t) >> 6;
    const int lane = t & 63;
    if (node >= NN) return;
    const int deg = min(deg_[node], CAP);
    const int li = lane & 31;
    const int half = lane >> 5;

    int   sidx = 0;
    float p    = 0.f;
    if (lane < deg) {
        sidx = csr[(node << 6) + lane];
        float e = als[sidx] + ald[node];
        e = fmaxf(e, NEG_SLOPE * e);
        e = fminf(e, 60.f);
        p = __expf(e);
    }
    float den = p;
#pragma unroll
    for (int m = 1; m < 64; m <<= 1) den += __shfl_xor(den, m);
    p *= 1.f / (den + 1e-16f);

    const unsigned int* x2 = (const unsigned int*)x;
    float a4[4] = {0.f, 0.f, 0.f, 0.f};
#pragma unroll
    for (int j0 = 0; j0 < CAP; j0 += 32) {
        if (j0 >= deg) break;
        unsigned long long u[16]; float pj[16];
#pragma unroll
        for (int k = 0; k < 16; ++k) {
            const int je = j0 + 2 * k;
            int ia = __builtin_amdgcn_readlane(sidx, je);
            int ib = __builtin_amdgcn_readlane(sidx, je + 1);
            float pa = readlane_f(p, je);
            float pb = readlane_f(p, je + 1);
            int isel = half ? ib : ia;
            pj[k] = half ? pb : pa;
            const unsigned long long* rowp =
                (const unsigned long long*)(x2 + (((size_t)(unsigned)isel) << 6));
            u[k] = rowp[li];
        }
#pragma unroll
        for (int k = 0; k < 16; ++k) {
            unsigned int lo32 = (unsigned int)u[k];
            unsigned int hi32 = (unsigned int)(u[k] >> 32);
            a4[0] = fmaf(pj[k], f_lo(lo32), a4[0]);
            a4[1] = fmaf(pj[k], f_hi(lo32), a4[1]);
            a4[2] = fmaf(pj[k], f_lo(hi32), a4[2]);
            a4[3] = fmaf(pj[k], f_hi(hi32), a4[3]);
        }
    }
#pragma unroll
    for (int c = 0; c < 4; ++c) a4[c] += __shfl_xor(a4[c], 32);

    const float4 bv4 = ((const float4*)bias)[li];
    float o0 = a4[0] + bv4.x;
    float o1 = a4[1] + bv4.y;
    float o2 = a4[2] + bv4.z;
    float o3 = a4[3] + bv4.w;
    if (half == 0) {
        if (hf) {
            ushort4 pk;
            pk.x = f2b(o0); pk.y = f2b(o1); pk.z = f2b(o2); pk.w = f2b(o3);
            *(ushort4*)((unsigned short*)out + (size_t)node * HID + li * 4) = pk;
        } else {
            *(float4*)((float*)out + (size_t)node * HID + li * 4) = make_float4(o0, o1, o2, o3);
        }
    }
}

extern "C" void kernel_launch(void* const* d_in, const int* in_sizes, int n_in,
                              void* d_out, int out_size, void* d_ws, size_t ws_size,
                              hipStream_t stream) {
    const unsigned short* z  = (const unsigned short*)d_in[0];
    const int*            ei = (const int*)d_in[1];
    const void*           Ws = d_in[2];
    const void*           as = d_in[3];
    const void*           ad = d_in[4];
    const void*           bb = d_in[5];

    char* wsp = (char*)d_ws;
    auto alloc = [&](size_t bytes) -> char* {
        char* p = wsp; wsp += (bytes + 255) & ~(size_t)255; return p;
    };
    int*            pos  = (int*)alloc(NN * 4);
    int*            csrp = (int*)alloc((size_t)NN * CAP * 4);    // padded CSR (12.8 MB)
    float*          alsA = (float*)alloc(NN * 4);
    float*          aldA = (float*)alloc(NN * 4);
    float*          alsB = (float*)alloc(NN * 4);
    float*          aldB = (float*)alloc(NN * 4);
    unsigned short* Wb   = (unsigned short*)alloc((size_t)3 * WL3 * 2);  // 3 forms x 3 layers
    float*          asf  = (float*)alloc(3 * HID * 4);
    float*          adf  = (float*)alloc(3 * HID * 4);
    float*          bff  = (float*)alloc(3 * HID * 4);
    unsigned short* xb0  = (unsigned short*)alloc((size_t)NN * HID * 2);  // x ping
    unsigned short* xb1  = (unsigned short*)alloc((size_t)NN * HID * 2);  // x pong

    // 1) prep: dtype + W forms + vectors + pos zero
    prep<<<197, 256, 0, stream>>>(z, Ws, as, ad, bb, Wb, asf, adf, bff, pos);

    // 2) gemm layer 0 (blocks first) + de-replicated scatter (overlapped)
    scat_gemm0<<<GEMM_VB + SCAT_BLKS, 256, 0, stream>>>(z, ei, Wb, asf, adf,
                                                        pos, csrp, xb0, alsA, aldA);

    // 3) agg(layer0) + gemm(layer1): xb0 -> xb1, alsA -> alsB
    agg_gemm<<<AG_VB, 512, 0, stream>>>(xb0, pos, csrp, alsA, aldA, bff,
                                        Wb + WL3 + 2 * HH, Wb + WL3 + HH,
                                        asf + HID, adf + HID, xb1, alsB, aldB);

    // 4) agg(layer1) + gemm(layer2): xb1 -> xb0, alsB -> alsA
    agg_gemm<<<AG_VB, 512, 0, stream>>>(xb1, pos, csrp, alsB, aldB, bff + HID,
                                        Wb + 2 * WL3 + 2 * HH, Wb + 2 * WL3 + HH,
                                        asf + 2 * HID, adf + 2 * HID, xb0, alsA, aldA);

    // 5) final aggregate (layer2, no relu) -> d_out
    agg_fin<<<(NN + 3) / 4, 256, 0, stream>>>(z, xb0, pos, csrp, alsA, aldA,
                                              bff + 2 * HID, d_out);
}

// Round 16
// 274.683 us; speedup vs baseline: 1.1674x; 1.1674x over previous
//
#include <hip/hip_runtime.h>

#define NN 50000
#define HID 128
#define HH (HID * HID)
#define NE 800000
#define ET (NE + NN)          // edges + self loops
#define NEG_SLOPE 0.2f
#define CAP 64                // padded CSR slots per node (max deg ~45)
#define WTOT (3 * HID * HID)  // 49152
#define VTOT (3 * 3 * HID)    // 1152
#define SCHUNK 1024
#define SCAT_BLKS ((ET + SCHUNK - 1) / SCHUNK)   // 831 (de-replicated: 1 block/chunk)
#define GEMM_VB ((NN + 63) / 64)                 // 782
#define AG_VB ((NN + 31) / 32)                   // 1563: 32-row tiles for fused agg+gemm
#define WL3 (3 * HH)          // per-layer Wb stride: [swz-hi][plain-lo][plain-hi]

typedef __attribute__((ext_vector_type(8))) short short8v;  // 8 bf16 = 4 VGPRs
typedef __attribute__((ext_vector_type(4))) float f32x4;    // MFMA accumulator

__device__ inline float b2f(unsigned short u) {
    union { unsigned int i; float f; } x; x.i = ((unsigned int)u) << 16; return x.f;
}
__device__ inline float f_lo(unsigned int u) {
    union { unsigned int i; float f; } x; x.i = u << 16; return x.f;
}
__device__ inline float f_hi(unsigned int u) {
    union { unsigned int i; float f; } x; x.i = u & 0xFFFF0000u; return x.f;
}
__device__ inline unsigned short f2b(float f) {
    unsigned int x; __builtin_memcpy(&x, &f, 4);
    unsigned int lsb = (x >> 16) & 1u;
    x += 0x7fffu + lsb;                  // round-to-nearest-even
    return (unsigned short)(x >> 16);
}
__device__ inline void splitbf(float v, unsigned short& hi, unsigned short& lo) {
    hi = f2b(v);
    lo = f2b(v - b2f(hi));
}
__device__ inline float readlane_f(float v, int l) {
    union { float f; int i; } x; x.f = v;
    x.i = __builtin_amdgcn_readlane(x.i, l);
    return x.f;
}
// block-local dtype probe (128 even-halfword samples of z); includes a barrier
__device__ __forceinline__ int probe_hf_dev(const unsigned short* z, int t, int* sflag) {
    if (t < 64) {
        unsigned short a = z[t * 4];
        unsigned short b = z[t * 4 + 2];
        int ea = (a >> 7) & 0xFF, eb = (b >> 7) & 0xFF;
        int w1 = (ea >= 0x9A || (ea <= 0x30 && a != 0)) ? 1 : 0;
        int w2 = (eb >= 0x9A || (eb <= 0x30 && b != 0)) ? 1 : 0;
        int wild = __popcll(__ballot(w1)) + __popcll(__ballot(w2));
        if (t == 0) *sflag = (wild < 8) ? 1 : 0;
    }
    __syncthreads();
    return *sflag;
}

// ---------- prep: dtype + W three forms + param vectors + pos zero ----------
__global__ __launch_bounds__(256) void prep(
        const unsigned short* __restrict__ z, const void* __restrict__ Ws,
        const void* __restrict__ as_, const void* __restrict__ ad_,
        const void* __restrict__ b_, unsigned short* __restrict__ Wb,
        float* __restrict__ asf, float* __restrict__ adf, float* __restrict__ bff,
        int* __restrict__ pos) {
    __shared__ int sflag;
    const int t = threadIdx.x;
    const int f = probe_hf_dev(z, t, &sflag);
    const int gtid = blockIdx.x * 256 + t;
    if (gtid < NN) pos[gtid] = 0;
    if (gtid < WTOT) {
        // per layer: [swz-hi 32KB LDS image][plain-lo W^T][plain-hi W^T], k contig
        int L = gtid >> 14, k = (gtid >> 7) & 127, n = gtid & 127;
        float v = f ? b2f(((const unsigned short*)Ws)[gtid]) : ((const float*)Ws)[gtid];
        unsigned short hi, lo;
        splitbf(v, hi, lo);
        unsigned short* hbase = Wb + (size_t)L * WL3;
        int bo = (n * 256 + k * 2) ^ ((n & 7) << 4);
        *(unsigned short*)((char*)hbase + bo) = hi;     // swizzled hi (LDS image)
        hbase[HH + n * HID + k]     = lo;               // plain lo
        hbase[2 * HH + n * HID + k] = hi;               // plain hi
    } else {
        int i = gtid - WTOT;
        if (i < VTOT) {
            int which = i / (3 * HID), j = i - which * (3 * HID);
            const void* in = which == 0 ? as_ : which == 1 ? ad_ : b_;
            float* o = which == 0 ? asf : which == 1 ? adf : bff;
            o[j] = f ? b2f(((const unsigned short*)in)[j]) : ((const float*)in)[j];
        }
    }
}

// ---------- merged gemm layer 0 (FIRST in grid) + CSR scatter (after) ----------
__global__ __launch_bounds__(256) void scat_gemm0(
        const unsigned short* __restrict__ z, const int* __restrict__ ei,
        const unsigned short* __restrict__ Wb, const float* __restrict__ a_s,
        const float* __restrict__ a_d, int* __restrict__ pos, int* __restrict__ csr,
        unsigned short* __restrict__ x, float* __restrict__ als, float* __restrict__ ald) {
    __shared__ unsigned short Wh[HH];   // 32 KB swizzled W-hi image
    __shared__ int sflag;
    const int t = threadIdx.x;

    if (blockIdx.x >= GEMM_VB) {        // ---- scatter branch (block-uniform) ----
        const int base = (blockIdx.x - GEMM_VB) * SCHUNK;
#pragma unroll
        for (int k = 0; k < SCHUNK / 256; ++k) {
            int e = base + k * 256 + t;
            if (e >= ET) continue;
            int d = (e < NE) ? ei[NE + e] : (e - NE);
            int s = (e < NE) ? ei[e] : d;
            int slot = atomicAdd(&pos[d], 1);
            if (slot < CAP) csr[(d << 6) + slot] = s;
        }
        return;
    }

    // ---- gemm layer 0 branch ----
    const int hf = probe_hf_dev(z, t, &sflag);
    const int base = blockIdx.x * 64;
    const unsigned short* Wlo = Wb + HH;
#pragma unroll
    for (int i = 0; i < 8; ++i) {
        int c = i * 256 + t;
        ((short8v*)Wh)[c] = ((const short8v*)Wb)[c];
    }
    __syncthreads();

    const int w  = t >> 6;
    const int l  = t & 63;
    const int lr = l & 15;
    const int lk = l >> 4;
    const int arow = base + w * 16 + lr;
    const bool rowok = (arow < NN);

    const short8v zv = (short8v){0, 0, 0, 0, 0, 0, 0, 0};
    short8v ahi[4], alo[4];
    if (hf) {
        const unsigned short* hp = z + (size_t)arow * HID + lk * 8;
#pragma unroll
        for (int ks = 0; ks < 4; ++ks) {
            ahi[ks] = rowok ? *(const short8v*)(hp + ks * 32) : zv;
            alo[ks] = zv;
        }
    } else {
        const float* hp = (const float*)z + (size_t)arow * HID + lk * 8;
#pragma unroll
        for (int ks = 0; ks < 4; ++ks) {
            float4 v0 = make_float4(0.f, 0.f, 0.f, 0.f), v1 = v0;
            if (rowok) {
                v0 = *(const float4*)(hp + ks * 32);
                v1 = *(const float4*)(hp + ks * 32 + 4);
            }
            ushort4 h0, l0, h1, l1;
            splitbf(v0.x, h0.x, l0.x); splitbf(v0.y, h0.y, l0.y);
            splitbf(v0.z, h0.z, l0.z); splitbf(v0.w, h0.w, l0.w);
            splitbf(v1.x, h1.x, l1.x); splitbf(v1.y, h1.y, l1.y);
            splitbf(v1.z, h1.z, l1.z); splitbf(v1.w, h1.w, l1.w);
            ahi[ks] = (short8v){(short)h0.x, (short)h0.y, (short)h0.z, (short)h0.w,
                                (short)h1.x, (short)h1.y, (short)h1.z, (short)h1.w};
            alo[ks] = (short8v){(short)l0.x, (short)l0.y, (short)l0.z, (short)l0.w,
                                (short)l1.x, (short)l1.y, (short)l1.z, (short)l1.w};
        }
    }

    f32x4 acc[8];
#pragma unroll
    for (int nt = 0; nt < 8; ++nt) acc[nt] = (f32x4){0.f, 0.f, 0.f, 0.f};

#pragma unroll
    for (int ks = 0; ks < 4; ++ks) {
#pragma unroll
        for (int nt = 0; nt < 8; ++nt) {
            int row = nt * 16 + lr;
            int bo = (row * 256 + ks * 64 + lk * 16) ^ ((lr & 7) << 4);
            short8v bhi = *(const short8v*)((const char*)Wh + bo);
            short8v blo = *(const short8v*)(Wlo + row * HID + ks * 32 + lk * 8);
            acc[nt] = __builtin_amdgcn_mfma_f32_16x16x32_bf16(ahi[ks], bhi, acc[nt], 0, 0, 0);
            if (!hf) acc[nt] = __builtin_amdgcn_mfma_f32_16x16x32_bf16(alo[ks], bhi, acc[nt], 0, 0, 0);
            acc[nt] = __builtin_amdgcn_mfma_f32_16x16x32_bf16(ahi[ks], blo, acc[nt], 0, 0, 0);
        }
    }

    float ps[4] = {0.f, 0.f, 0.f, 0.f};
    float pd[4] = {0.f, 0.f, 0.f, 0.f};
#pragma unroll
    for (int nt = 0; nt < 8; ++nt) {
        float asv = a_s[nt * 16 + lr];
        float adv = a_d[nt * 16 + lr];
#pragma unroll
        for (int r = 0; r < 4; ++r) {
            ps[r] = fmaf(acc[nt][r], asv, ps[r]);
            pd[r] = fmaf(acc[nt][r], adv, pd[r]);
        }
    }
#pragma unroll
    for (int m = 8; m >= 1; m >>= 1) {
#pragma unroll
        for (int r = 0; r < 4; ++r) {
            ps[r] += __shfl_xor(ps[r], m, 16);
            pd[r] += __shfl_xor(pd[r], m, 16);
        }
    }
#pragma unroll
    for (int r = 0; r < 4; ++r) {
        int grow = base + w * 16 + lk * 4 + r;
        if (grow < NN) {
#pragma unroll
            for (int nt = 0; nt < 8; ++nt)
                x[(size_t)grow * HID + nt * 16 + lr] = f2b(acc[nt][r]);
            if (lr == 0) { als[grow] = ps[r]; ald[grow] = pd[r]; }
        }
    }
}

// ---------- fused aggregate(L) + gemm(L+1) (R13 best config, verbatim) ----------
// 1563 blocks x 512 threads; 8 waves, 4 serial nodes/wave; readlane
// distribution (one exp/edge, register-resident (idx,p)); A from swizzled LDS,
// B plain global (L2-hot). R14 (interleaved-node) and R15 (dual-edge 8-B)
// both REGRESSED (67.5 / 80.4 vs 60.3 us) -> this gather loop is at its
// practical limit (L3-bound: 12.8 MB x-array thrashes 4 MB per-XCD L2).
__global__ __launch_bounds__(512) void agg_gemm(
        const unsigned short* __restrict__ xin, const int* __restrict__ deg_,
        const int* __restrict__ csr, const float* __restrict__ als_in,
        const float* __restrict__ ald_in, const float* __restrict__ bias,
        const unsigned short* __restrict__ Whip, const unsigned short* __restrict__ Wlop,
        const float* __restrict__ a_s, const float* __restrict__ a_d,
        unsigned short* __restrict__ xout, float* __restrict__ als_out,
        float* __restrict__ ald_out) {
    __shared__ unsigned short Ah[32 * HID];   // 8 KB h-hi, swizzled
    __shared__ unsigned short Al[32 * HID];   // 8 KB h-lo, swizzled
    __shared__ float aps[32][4], apd[32][4];  // cross-wc alpha partials (1 KB)
    const int t = threadIdx.x;
    const int base = blockIdx.x * 32;
    const int w = t >> 6;                     // 8 waves
    const int lane = t & 63;
    const unsigned int* x2 = (const unsigned int*)xin;
    const float2 bv = ((const float2*)bias)[lane];

    // ---- agg phase: 4 nodes per wave ----
    for (int i = 0; i < 4; ++i) {
        const int r = w * 4 + i;                     // tile row 0..31
        const int node = base + r;
        const int deg = (node < NN) ? min(deg_[node], CAP) : 0;
        int   sidx = 0;
        float p    = 0.f;
        if (lane < deg) {
            sidx = csr[(node << 6) + lane];
            float e = als_in[sidx] + ald_in[node];
            e = fmaxf(e, NEG_SLOPE * e);             // leaky_relu
            e = fminf(e, 60.f);                      // inf hardening
            p = __expf(e);
        }
        float den = p;
#pragma unroll
        for (int m = 1; m < 64; m <<= 1) den += __shfl_xor(den, m);
        p *= 1.f / (den + 1e-16f);

        float ax = 0.f, ay = 0.f;
#pragma unroll
        for (int j0 = 0; j0 < CAP; j0 += 16) {
            if (j0 >= deg) break;                    // wave-uniform group skip
            unsigned int u[16]; float pj[16];
#pragma unroll
            for (int k = 0; k < 16; ++k) {
                const int j = j0 + k;
                int ijs = __builtin_amdgcn_readlane(sidx, j);
                pj[k] = readlane_f(p, j);
                const unsigned int* rowp = x2 + (((size_t)(unsigned)ijs) << 6);
                u[k] = rowp[lane];
            }
#pragma unroll
            for (int k = 0; k < 16; ++k) {
                ax = fmaf(pj[k], f_lo(u[k]), ax);
                ay = fmaf(pj[k], f_hi(u[k]), ay);
            }
        }
        float ox = fmaxf(ax + bv.x, 0.f);            // relu (fused layers are 0/1)
        float oy = fmaxf(ay + bv.y, 0.f);
        unsigned short hx, lx, hy, ly;
        splitbf(ox, hx, lx); splitbf(oy, hy, ly);
        const int bo = (r * 256 + lane * 4) ^ ((r & 7) << 4);  // 4-B aligned
        ushort2 ph; ph.x = hx; ph.y = hy;
        ushort2 pl; pl.x = lx; pl.y = ly;
        *(ushort2*)((char*)Ah + bo) = ph;
        *(ushort2*)((char*)Al + bo) = pl;
    }
    __syncthreads();    // all h rows visible to all waves

    // ---- gemm phase: wave (wr,wc) = 16 rows x 32 cols; A LDS, B global ----
    const int wr = w & 1;
    const int wc = w >> 1;        // 0..3
    const int lr = lane & 15;
    const int lk = lane >> 4;
    const int ar = wr * 16 + lr;
    short8v ahi[4], alo[4];
#pragma unroll
    for (int ks = 0; ks < 4; ++ks) {
        int ab = (ar * 256 + ks * 64 + lk * 16) ^ ((ar & 7) << 4);
        ahi[ks] = *(const short8v*)((const char*)Ah + ab);
        alo[ks] = *(const short8v*)((const char*)Al + ab);
    }

    f32x4 acc[2];
#pragma unroll
    for (int nt = 0; nt < 2; ++nt) acc[nt] = (f32x4){0.f, 0.f, 0.f, 0.f};

#pragma unroll
    for (int ks = 0; ks < 4; ++ks) {
#pragma unroll
        for (int nt = 0; nt < 2; ++nt) {
            int row = wc * 32 + nt * 16 + lr;
            short8v bhi = *(const short8v*)(Whip + row * HID + ks * 32 + lk * 8);
            short8v blo = *(const short8v*)(Wlop + row * HID + ks * 32 + lk * 8);
            acc[nt] = __builtin_amdgcn_mfma_f32_16x16x32_bf16(ahi[ks], bhi, acc[nt], 0, 0, 0);
            acc[nt] = __builtin_amdgcn_mfma_f32_16x16x32_bf16(alo[ks], bhi, acc[nt], 0, 0, 0);
            acc[nt] = __builtin_amdgcn_mfma_f32_16x16x32_bf16(ahi[ks], blo, acc[nt], 0, 0, 0);
        }
    }

    // ---- epilogue: alpha partials (this wave's 32 cols) + 4-way wc combine ----
    float ps[4] = {0.f, 0.f, 0.f, 0.f};
    float pd[4] = {0.f, 0.f, 0.f, 0.f};
#pragma unroll
    for (int nt = 0; nt < 2; ++nt) {
        float asv = a_s[wc * 32 + nt * 16 + lr];
        float adv = a_d[wc * 32 + nt * 16 + lr];
#pragma unroll
        for (int r = 0; r < 4; ++r) {
            ps[r] = fmaf(acc[nt][r], asv, ps[r]);
            pd[r] = fmaf(acc[nt][r], adv, pd[r]);
        }
    }
#pragma unroll
    for (int m = 8; m >= 1; m >>= 1) {
#pragma unroll
        for (int r = 0; r < 4; ++r) {
            ps[r] += __shfl_xor(ps[r], m, 16);
            pd[r] += __shfl_xor(pd[r], m, 16);
        }
    }
    if (lr == 0) {
#pragma unroll
        for (int r = 0; r < 4; ++r) {
            int rib = wr * 16 + lk * 4 + r;
            aps[rib][wc] = ps[r];
            apd[rib][wc] = pd[r];
        }
    }
    __syncthreads();

#pragma unroll
    for (int r = 0; r < 4; ++r) {
        int rib = wr * 16 + lk * 4 + r;
        int grow = base + rib;
        if (grow < NN) {
#pragma unroll
            for (int nt = 0; nt < 2; ++nt)
                xout[(size_t)grow * HID + wc * 32 + nt * 16 + lr] = f2b(acc[nt][r]);
            if (wc == 0 && lr == 0) {
                als_out[grow] = (aps[rib][0] + aps[rib][1]) + (aps[rib][2] + aps[rib][3]);
                ald_out[grow] = (apd[rib][0] + apd[rib][1]) + (apd[rib][2] + apd[rib][3]);
            }
        }
    }
}

// ---------- final aggregate (layer 2, no relu) -> d_out ----------
__global__ __launch_bounds__(256) void agg_fin(
        const unsigned short* __restrict__ z, const unsigned short* __restrict__ x,
        const int* __restrict__ deg_, const int* __restrict__ csr,
        const float* __restrict__ als, const float* __restrict__ ald,
        const float* __restrict__ bias, void* __restrict__ out) {
    __shared__ int sflag;
    const int t = threadIdx.x;
    const int hf = probe_hf_dev(z, t, &sflag);
    const int node = (blockIdx.x * 256 + t) >> 6;
    const int lane = t & 63;
    if (node >= NN) return;
    const int deg = min(deg_[node], CAP);

    int   sidx = 0;
    float p    = 0.f;
    if (lane < deg) {
        sidx = csr[(node << 6) + lane];
        float e = als[sidx] + ald[node];
        e = fmaxf(e, NEG_SLOPE * e);
        e = fminf(e, 60.f);
        p = __expf(e);
    }
    float den = p;
#pragma unroll
    for (int m = 1; m < 64; m <<= 1) den += __shfl_xor(den, m);
    p *= 1.f / (den + 1e-16f);

    const unsigned int* x2 = (const unsigned int*)x;
    float ax = 0.f, ay = 0.f;
#pragma unroll
    for (int j0 = 0; j0 < CAP; j0 += 16) {
        if (j0 >= deg) break;
        unsigned int u[16]; float pj[16];
#pragma unroll
        for (int k = 0; k < 16; ++k) {
            const int j = j0 + k;
            int ijs = __builtin_amdgcn_readlane(sidx, j);
            pj[k] = readlane_f(p, j);
            const unsigned int* rowp = x2 + (((size_t)(unsigned)ijs) << 6);
            u[k] = rowp[lane];
        }
#pragma unroll
        for (int k = 0; k < 16; ++k) {
            ax = fmaf(pj[k], f_lo(u[k]), ax);
            ay = fmaf(pj[k], f_hi(u[k]), ay);
        }
    }

    float2 bv = ((const float2*)bias)[lane];
    float ox = ax + bv.x;
    float oy = ay + bv.y;
    if (hf) {
        ushort2 pk; pk.x = f2b(ox); pk.y = f2b(oy);
        *(ushort2*)((unsigned short*)out + (size_t)node * HID + lane * 2) = pk;
    } else {
        ((float2*)out)[(size_t)node * 64 + lane] = make_float2(ox, oy);
    }
}

extern "C" void kernel_launch(void* const* d_in, const int* in_sizes, int n_in,
                              void* d_out, int out_size, void* d_ws, size_t ws_size,
                              hipStream_t stream) {
    const unsigned short* z  = (const unsigned short*)d_in[0];
    const int*            ei = (const int*)d_in[1];
    const void*           Ws = d_in[2];
    const void*           as = d_in[3];
    const void*           ad = d_in[4];
    const void*           bb = d_in[5];

    char* wsp = (char*)d_ws;
    auto alloc = [&](size_t bytes) -> char* {
        char* p = wsp; wsp += (bytes + 255) & ~(size_t)255; return p;
    };
    int*            pos  = (int*)alloc(NN * 4);
    int*            csrp = (int*)alloc((size_t)NN * CAP * 4);    // padded CSR (12.8 MB)
    float*          alsA = (float*)alloc(NN * 4);
    float*          aldA = (float*)alloc(NN * 4);
    float*          alsB = (float*)alloc(NN * 4);
    float*          aldB = (float*)alloc(NN * 4);
    unsigned short* Wb   = (unsigned short*)alloc((size_t)3 * WL3 * 2);  // 3 forms x 3 layers
    float*          asf  = (float*)alloc(3 * HID * 4);
    float*          adf  = (float*)alloc(3 * HID * 4);
    float*          bff  = (float*)alloc(3 * HID * 4);
    unsigned short* xb0  = (unsigned short*)alloc((size_t)NN * HID * 2);  // x ping
    unsigned short* xb1  = (unsigned short*)alloc((size_t)NN * HID * 2);  // x pong

    // 1) prep: dtype + W forms + vectors + pos zero
    prep<<<197, 256, 0, stream>>>(z, Ws, as, ad, bb, Wb, asf, adf, bff, pos);

    // 2) gemm layer 0 (blocks first) + de-replicated scatter (overlapped)
    scat_gemm0<<<GEMM_VB + SCAT_BLKS, 256, 0, stream>>>(z, ei, Wb, asf, adf,
                                                        pos, csrp, xb0, alsA, aldA);

    // 3) agg(layer0) + gemm(layer1): xb0 -> xb1, alsA -> alsB
    agg_gemm<<<AG_VB, 512, 0, stream>>>(xb0, pos, csrp, alsA, aldA, bff,
                                        Wb + WL3 + 2 * HH, Wb + WL3 + HH,
                                        asf + HID, adf + HID, xb1, alsB, aldB);

    // 4) agg(layer1) + gemm(layer2): xb1 -> xb0, alsB -> alsA
    agg_gemm<<<AG_VB, 512, 0, stream>>>(xb1, pos, csrp, alsB, aldB, bff + HID,
                                        Wb + 2 * WL3 + 2 * HH, Wb + 2 * WL3 + HH,
                                        asf + 2 * HID, adf + 2 * HID, xb0, alsA, aldA);

    // 5) final aggregate (layer2, no relu) -> d_out
    agg_fin<<<(NN + 3) / 4, 256, 0, stream>>>(z, xb0, pos, csrp, alsA, aldA,
                                              bff + 2 * HID, d_out);
}

// Round 17
// 274.184 us; speedup vs baseline: 1.1696x; 1.0018x over previous
//
#include <hip/hip_runtime.h>

#define NN 50000
#define HID 128
#define HH (HID * HID)
#define NE 800000
#define ET (NE + NN)          // edges + self loops
#define NEG_SLOPE 0.2f
#define CAP 64                // padded CSR slots per node (max deg ~45)
#define WTOT (3 * HID * HID)  // 49152
#define VTOT (3 * 3 * HID)    // 1152
#define SCHUNK 1024
#define SCAT_BLKS ((ET + SCHUNK - 1) / SCHUNK)   // 831 (de-replicated: 1 block/chunk)
#define GEMM_VB ((NN + 63) / 64)                 // 782
#define AG_VB ((NN + 31) / 32)                   // 1563: 32-row tiles for fused agg+gemm
#define WL3 (3 * HH)          // per-layer Wb stride: [swz-hi][plain-lo][plain-hi]

typedef __attribute__((ext_vector_type(8))) short short8v;  // 8 bf16 = 4 VGPRs
typedef __attribute__((ext_vector_type(4))) float f32x4;    // MFMA accumulator

__device__ inline float b2f(unsigned short u) {
    union { unsigned int i; float f; } x; x.i = ((unsigned int)u) << 16; return x.f;
}
__device__ inline float f_lo(unsigned int u) {
    union { unsigned int i; float f; } x; x.i = u << 16; return x.f;
}
__device__ inline float f_hi(unsigned int u) {
    union { unsigned int i; float f; } x; x.i = u & 0xFFFF0000u; return x.f;
}
__device__ inline unsigned short f2b(float f) {
    unsigned int x; __builtin_memcpy(&x, &f, 4);
    unsigned int lsb = (x >> 16) & 1u;
    x += 0x7fffu + lsb;                  // round-to-nearest-even
    return (unsigned short)(x >> 16);
}
__device__ inline void splitbf(float v, unsigned short& hi, unsigned short& lo) {
    hi = f2b(v);
    lo = f2b(v - b2f(hi));
}
__device__ inline float readlane_f(float v, int l) {
    union { float f; int i; } x; x.f = v;
    x.i = __builtin_amdgcn_readlane(x.i, l);
    return x.f;
}
// block-local dtype probe (128 even-halfword samples of z); includes a barrier
__device__ __forceinline__ int probe_hf_dev(const unsigned short* z, int t, int* sflag) {
    if (t < 64) {
        unsigned short a = z[t * 4];
        unsigned short b = z[t * 4 + 2];
        int ea = (a >> 7) & 0xFF, eb = (b >> 7) & 0xFF;
        int w1 = (ea >= 0x9A || (ea <= 0x30 && a != 0)) ? 1 : 0;
        int w2 = (eb >= 0x9A || (eb <= 0x30 && b != 0)) ? 1 : 0;
        int wild = __popcll(__ballot(w1)) + __popcll(__ballot(w2));
        if (t == 0) *sflag = (wild < 8) ? 1 : 0;
    }
    __syncthreads();
    return *sflag;
}

// ---------- prep: dtype + W three forms + param vectors + pos zero ----------
__global__ __launch_bounds__(256) void prep(
        const unsigned short* __restrict__ z, const void* __restrict__ Ws,
        const void* __restrict__ as_, const void* __restrict__ ad_,
        const void* __restrict__ b_, unsigned short* __restrict__ Wb,
        float* __restrict__ asf, float* __restrict__ adf, float* __restrict__ bff,
        int* __restrict__ pos) {
    __shared__ int sflag;
    const int t = threadIdx.x;
    const int f = probe_hf_dev(z, t, &sflag);
    const int gtid = blockIdx.x * 256 + t;
    if (gtid < NN) pos[gtid] = 0;
    if (gtid < WTOT) {
        // per layer: [swz-hi 32KB LDS image][plain-lo W^T][plain-hi W^T], k contig
        int L = gtid >> 14, k = (gtid >> 7) & 127, n = gtid & 127;
        float v = f ? b2f(((const unsigned short*)Ws)[gtid]) : ((const float*)Ws)[gtid];
        unsigned short hi, lo;
        splitbf(v, hi, lo);
        unsigned short* hbase = Wb + (size_t)L * WL3;
        int bo = (n * 256 + k * 2) ^ ((n & 7) << 4);
        *(unsigned short*)((char*)hbase + bo) = hi;     // swizzled hi (LDS image)
        hbase[HH + n * HID + k]     = lo;               // plain lo
        hbase[2 * HH + n * HID + k] = hi;               // plain hi
    } else {
        int i = gtid - WTOT;
        if (i < VTOT) {
            int which = i / (3 * HID), j = i - which * (3 * HID);
            const void* in = which == 0 ? as_ : which == 1 ? ad_ : b_;
            float* o = which == 0 ? asf : which == 1 ? adf : bff;
            o[j] = f ? b2f(((const unsigned short*)in)[j]) : ((const float*)in)[j];
        }
    }
}

// ---------- merged gemm layer 0 + CSR scatter, v2: NO LDS W-staging ----------
// R16 counters: 60.5 us at Occupancy 29% / VALU 7% -- the kernel's static
// 32-KB LDS (used only by gemm blocks) capped ALL blocks at 4/CU, choking the
// latency-bound scatter blocks. Fix: gemm reads bhi from plain-hi global
// (Wb+2HH) and blo from plain-lo (Wb+HH), both L2-hot (64 KB shared by 782
// blocks; R7 measured the no-LDS B-path at ~+4 us for the gemm alone).
// LDS -> ~0 => 8 blocks/CU => 2x scatter latency-hiding. Identical B values,
// identical ks/nt accumulation order -> x bitwise unchanged.
__global__ __launch_bounds__(256) void scat_gemm0(
        const unsigned short* __restrict__ z, const int* __restrict__ ei,
        const unsigned short* __restrict__ Wb, const float* __restrict__ a_s,
        const float* __restrict__ a_d, int* __restrict__ pos, int* __restrict__ csr,
        unsigned short* __restrict__ x, float* __restrict__ als, float* __restrict__ ald) {
    __shared__ int sflag;
    const int t = threadIdx.x;

    if (blockIdx.x >= GEMM_VB) {        // ---- scatter branch (block-uniform) ----
        const int base = (blockIdx.x - GEMM_VB) * SCHUNK;
#pragma unroll
        for (int k = 0; k < SCHUNK / 256; ++k) {
            int e = base + k * 256 + t;
            if (e >= ET) continue;
            int d = (e < NE) ? ei[NE + e] : (e - NE);
            int s = (e < NE) ? ei[e] : d;
            int slot = atomicAdd(&pos[d], 1);
            if (slot < CAP) csr[(d << 6) + slot] = s;
        }
        return;
    }

    // ---- gemm layer 0 branch ----
    const int hf = probe_hf_dev(z, t, &sflag);
    const int base = blockIdx.x * 64;
    const unsigned short* Wlo = Wb + HH;        // plain lo, k-contig
    const unsigned short* Whi = Wb + 2 * HH;    // plain hi, k-contig

    const int w  = t >> 6;
    const int l  = t & 63;
    const int lr = l & 15;
    const int lk = l >> 4;
    const int arow = base + w * 16 + lr;
    const bool rowok = (arow < NN);

    const short8v zv = (short8v){0, 0, 0, 0, 0, 0, 0, 0};
    short8v ahi[4], alo[4];
    if (hf) {
        const unsigned short* hp = z + (size_t)arow * HID + lk * 8;
#pragma unroll
        for (int ks = 0; ks < 4; ++ks) {
            ahi[ks] = rowok ? *(const short8v*)(hp + ks * 32) : zv;
            alo[ks] = zv;
        }
    } else {
        const float* hp = (const float*)z + (size_t)arow * HID + lk * 8;
#pragma unroll
        for (int ks = 0; ks < 4; ++ks) {
            float4 v0 = make_float4(0.f, 0.f, 0.f, 0.f), v1 = v0;
            if (rowok) {
                v0 = *(const float4*)(hp + ks * 32);
                v1 = *(const float4*)(hp + ks * 32 + 4);
            }
            ushort4 h0, l0, h1, l1;
            splitbf(v0.x, h0.x, l0.x); splitbf(v0.y, h0.y, l0.y);
            splitbf(v0.z, h0.z, l0.z); splitbf(v0.w, h0.w, l0.w);
            splitbf(v1.x, h1.x, l1.x); splitbf(v1.y, h1.y, l1.y);
            splitbf(v1.z, h1.z, l1.z); splitbf(v1.w, h1.w, l1.w);
            ahi[ks] = (short8v){(short)h0.x, (short)h0.y, (short)h0.z, (short)h0.w,
                                (short)h1.x, (short)h1.y, (short)h1.z, (short)h1.w};
            alo[ks] = (short8v){(short)l0.x, (short)l0.y, (short)l0.z, (short)l0.w,
                                (short)l1.x, (short)l1.y, (short)l1.z, (short)l1.w};
        }
    }

    f32x4 acc[8];
#pragma unroll
    for (int nt = 0; nt < 8; ++nt) acc[nt] = (f32x4){0.f, 0.f, 0.f, 0.f};

#pragma unroll
    for (int ks = 0; ks < 4; ++ks) {
#pragma unroll
        for (int nt = 0; nt < 8; ++nt) {
            int row = nt * 16 + lr;
            short8v bhi = *(const short8v*)(Whi + row * HID + ks * 32 + lk * 8);
            short8v blo = *(const short8v*)(Wlo + row * HID + ks * 32 + lk * 8);
            acc[nt] = __builtin_amdgcn_mfma_f32_16x16x32_bf16(ahi[ks], bhi, acc[nt], 0, 0, 0);
            if (!hf) acc[nt] = __builtin_amdgcn_mfma_f32_16x16x32_bf16(alo[ks], bhi, acc[nt], 0, 0, 0);
            acc[nt] = __builtin_amdgcn_mfma_f32_16x16x32_bf16(ahi[ks], blo, acc[nt], 0, 0, 0);
        }
    }

    float ps[4] = {0.f, 0.f, 0.f, 0.f};
    float pd[4] = {0.f, 0.f, 0.f, 0.f};
#pragma unroll
    for (int nt = 0; nt < 8; ++nt) {
        float asv = a_s[nt * 16 + lr];
        float adv = a_d[nt * 16 + lr];
#pragma unroll
        for (int r = 0; r < 4; ++r) {
            ps[r] = fmaf(acc[nt][r], asv, ps[r]);
            pd[r] = fmaf(acc[nt][r], adv, pd[r]);
        }
    }
#pragma unroll
    for (int m = 8; m >= 1; m >>= 1) {
#pragma unroll
        for (int r = 0; r < 4; ++r) {
            ps[r] += __shfl_xor(ps[r], m, 16);
            pd[r] += __shfl_xor(pd[r], m, 16);
        }
    }
#pragma unroll
    for (int r = 0; r < 4; ++r) {
        int grow = base + w * 16 + lk * 4 + r;
        if (grow < NN) {
#pragma unroll
            for (int nt = 0; nt < 8; ++nt)
                x[(size_t)grow * HID + nt * 16 + lr] = f2b(acc[nt][r]);
            if (lr == 0) { als[grow] = ps[r]; ald[grow] = pd[r]; }
        }
    }
}

// ---------- fused aggregate(L) + gemm(L+1) (R13 best config, verbatim) ----------
// 1563 blocks x 512 threads; 8 waves, 4 serial nodes/wave; readlane
// distribution (one exp/edge, register-resident (idx,p)); A from swizzled LDS,
// B plain global (L2-hot). R14 (interleaved-node) and R15 (dual-edge 8-B)
// both REGRESSED (67.5 / 80.4 vs 60.3 us) -> this gather loop is at its
// practical limit (L2-miss-bound: 12.8 MB x-array thrashes 4 MB per-XCD L2).
__global__ __launch_bounds__(512) void agg_gemm(
        const unsigned short* __restrict__ xin, const int* __restrict__ deg_,
        const int* __restrict__ csr, const float* __restrict__ als_in,
        const float* __restrict__ ald_in, const float* __restrict__ bias,
        const unsigned short* __restrict__ Whip, const unsigned short* __restrict__ Wlop,
        const float* __restrict__ a_s, const float* __restrict__ a_d,
        unsigned short* __restrict__ xout, float* __restrict__ als_out,
        float* __restrict__ ald_out) {
    __shared__ unsigned short Ah[32 * HID];   // 8 KB h-hi, swizzled
    __shared__ unsigned short Al[32 * HID];   // 8 KB h-lo, swizzled
    __shared__ float aps[32][4], apd[32][4];  // cross-wc alpha partials (1 KB)
    const int t = threadIdx.x;
    const int base = blockIdx.x * 32;
    const int w = t >> 6;                     // 8 waves
    const int lane = t & 63;
    const unsigned int* x2 = (const unsigned int*)xin;
    const float2 bv = ((const float2*)bias)[lane];

    // ---- agg phase: 4 nodes per wave ----
    for (int i = 0; i < 4; ++i) {
        const int r = w * 4 + i;                     // tile row 0..31
        const int node = base + r;
        const int deg = (node < NN) ? min(deg_[node], CAP) : 0;
        int   sidx = 0;
        float p    = 0.f;
        if (lane < deg) {
            sidx = csr[(node << 6) + lane];
            float e = als_in[sidx] + ald_in[node];
            e = fmaxf(e, NEG_SLOPE * e);             // leaky_relu
            e = fminf(e, 60.f);                      // inf hardening
            p = __expf(e);
        }
        float den = p;
#pragma unroll
        for (int m = 1; m < 64; m <<= 1) den += __shfl_xor(den, m);
        p *= 1.f / (den + 1e-16f);

        float ax = 0.f, ay = 0.f;
#pragma unroll
        for (int j0 = 0; j0 < CAP; j0 += 16) {
            if (j0 >= deg) break;                    // wave-uniform group skip
            unsigned int u[16]; float pj[16];
#pragma unroll
            for (int k = 0; k < 16; ++k) {
                const int j = j0 + k;
                int ijs = __builtin_amdgcn_readlane(sidx, j);
                pj[k] = readlane_f(p, j);
                const unsigned int* rowp = x2 + (((size_t)(unsigned)ijs) << 6);
                u[k] = rowp[lane];
            }
#pragma unroll
            for (int k = 0; k < 16; ++k) {
                ax = fmaf(pj[k], f_lo(u[k]), ax);
                ay = fmaf(pj[k], f_hi(u[k]), ay);
            }
        }
        float ox = fmaxf(ax + bv.x, 0.f);            // relu (fused layers are 0/1)
        float oy = fmaxf(ay + bv.y, 0.f);
        unsigned short hx, lx, hy, ly;
        splitbf(ox, hx, lx); splitbf(oy, hy, ly);
        const int bo = (r * 256 + lane * 4) ^ ((r & 7) << 4);  // 4-B aligned
        ushort2 ph; ph.x = hx; ph.y = hy;
        ushort2 pl; pl.x = lx; pl.y = ly;
        *(ushort2*)((char*)Ah + bo) = ph;
        *(ushort2*)((char*)Al + bo) = pl;
    }
    __syncthreads();    // all h rows visible to all waves

    // ---- gemm phase: wave (wr,wc) = 16 rows x 32 cols; A LDS, B global ----
    const int wr = w & 1;
    const int wc = w >> 1;        // 0..3
    const int lr = lane & 15;
    const int lk = lane >> 4;
    const int ar = wr * 16 + lr;
    short8v ahi[4], alo[4];
#pragma unroll
    for (int ks = 0; ks < 4; ++ks) {
        int ab = (ar * 256 + ks * 64 + lk * 16) ^ ((ar & 7) << 4);
        ahi[ks] = *(const short8v*)((const char*)Ah + ab);
        alo[ks] = *(const short8v*)((const char*)Al + ab);
    }

    f32x4 acc[2];
#pragma unroll
    for (int nt = 0; nt < 2; ++nt) acc[nt] = (f32x4){0.f, 0.f, 0.f, 0.f};

#pragma unroll
    for (int ks = 0; ks < 4; ++ks) {
#pragma unroll
        for (int nt = 0; nt < 2; ++nt) {
            int row = wc * 32 + nt * 16 + lr;
            short8v bhi = *(const short8v*)(Whip + row * HID + ks * 32 + lk * 8);
            short8v blo = *(const short8v*)(Wlop + row * HID + ks * 32 + lk * 8);
            acc[nt] = __builtin_amdgcn_mfma_f32_16x16x32_bf16(ahi[ks], bhi, acc[nt], 0, 0, 0);
            acc[nt] = __builtin_amdgcn_mfma_f32_16x16x32_bf16(alo[ks], bhi, acc[nt], 0, 0, 0);
            acc[nt] = __builtin_amdgcn_mfma_f32_16x16x32_bf16(ahi[ks], blo, acc[nt], 0, 0, 0);
        }
    }

    // ---- epilogue: alpha partials (this wave's 32 cols) + 4-way wc combine ----
    float ps[4] = {0.f, 0.f, 0.f, 0.f};
    float pd[4] = {0.f, 0.f, 0.f, 0.f};
#pragma unroll
    for (int nt = 0; nt < 2; ++nt) {
        float asv = a_s[wc * 32 + nt * 16 + lr];
        float adv = a_d[wc * 32 + nt * 16 + lr];
#pragma unroll
        for (int r = 0; r < 4; ++r) {
            ps[r] = fmaf(acc[nt][r], asv, ps[r]);
            pd[r] = fmaf(acc[nt][r], adv, pd[r]);
        }
    }
#pragma unroll
    for (int m = 8; m >= 1; m >>= 1) {
#pragma unroll
        for (int r = 0; r < 4; ++r) {
            ps[r] += __shfl_xor(ps[r], m, 16);
            pd[r] += __shfl_xor(pd[r], m, 16);
        }
    }
    if (lr == 0) {
#pragma unroll
        for (int r = 0; r < 4; ++r) {
            int rib = wr * 16 + lk * 4 + r;
            aps[rib][wc] = ps[r];
            apd[rib][wc] = pd[r];
        }
    }
    __syncthreads();

#pragma unroll
    for (int r = 0; r < 4; ++r) {
        int rib = wr * 16 + lk * 4 + r;
        int grow = base + rib;
        if (grow < NN) {
#pragma unroll
            for (int nt = 0; nt < 2; ++nt)
                xout[(size_t)grow * HID + wc * 32 + nt * 16 + lr] = f2b(acc[nt][r]);
            if (wc == 0 && lr == 0) {
                als_out[grow] = (aps[rib][0] + aps[rib][1]) + (aps[rib][2] + aps[rib][3]);
                ald_out[grow] = (apd[rib][0] + apd[rib][1]) + (apd[rib][2] + apd[rib][3]);
            }
        }
    }
}

// ---------- final aggregate (layer 2, no relu) -> d_out ----------
__global__ __launch_bounds__(256) void agg_fin(
        const unsigned short* __restrict__ z, const unsigned short* __restrict__ x,
        const int* __restrict__ deg_, const int* __restrict__ csr,
        const float* __restrict__ als, const float* __restrict__ ald,
        const float* __restrict__ bias, void* __restrict__ out) {
    __shared__ int sflag;
    const int t = threadIdx.x;
    const int hf = probe_hf_dev(z, t, &sflag);
    const int node = (blockIdx.x * 256 + t) >> 6;
    const int lane = t & 63;
    if (node >= NN) return;
    const int deg = min(deg_[node], CAP);

    int   sidx = 0;
    float p    = 0.f;
    if (lane < deg) {
        sidx = csr[(node << 6) + lane];
        float e = als[sidx] + ald[node];
        e = fmaxf(e, NEG_SLOPE * e);
        e = fminf(e, 60.f);
        p = __expf(e);
    }
    float den = p;
#pragma unroll
    for (int m = 1; m < 64; m <<= 1) den += __shfl_xor(den, m);
    p *= 1.f / (den + 1e-16f);

    const unsigned int* x2 = (const unsigned int*)x;
    float ax = 0.f, ay = 0.f;
#pragma unroll
    for (int j0 = 0; j0 < CAP; j0 += 16) {
        if (j0 >= deg) break;
        unsigned int u[16]; float pj[16];
#pragma unroll
        for (int k = 0; k < 16; ++k) {
            const int j = j0 + k;
            int ijs = __builtin_amdgcn_readlane(sidx, j);
            pj[k] = readlane_f(p, j);
            const unsigned int* rowp = x2 + (((size_t)(unsigned)ijs) << 6);
            u[k] = rowp[lane];
        }
#pragma unroll
        for (int k = 0; k < 16; ++k) {
            ax = fmaf(pj[k], f_lo(u[k]), ax);
            ay = fmaf(pj[k], f_hi(u[k]), ay);
        }
    }

    float2 bv = ((const float2*)bias)[lane];
    float ox = ax + bv.x;
    float oy = ay + bv.y;
    if (hf) {
        ushort2 pk; pk.x = f2b(ox); pk.y = f2b(oy);
        *(ushort2*)((unsigned short*)out + (size_t)node * HID + lane * 2) = pk;
    } else {
        ((float2*)out)[(size_t)node * 64 + lane] = make_float2(ox, oy);
    }
}

extern "C" void kernel_launch(void* const* d_in, const int* in_sizes, int n_in,
                              void* d_out, int out_size, void* d_ws, size_t ws_size,
                              hipStream_t stream) {
    const unsigned short* z  = (const unsigned short*)d_in[0];
    const int*            ei = (const int*)d_in[1];
    const void*           Ws = d_in[2];
    const void*           as = d_in[3];
    const void*           ad = d_in[4];
    const void*           bb = d_in[5];

    char* wsp = (char*)d_ws;
    auto alloc = [&](size_t bytes) -> char* {
        char* p = wsp; wsp += (bytes + 255) & ~(size_t)255; return p;
    };
    int*            pos  = (int*)alloc(NN * 4);
    int*            csrp = (int*)alloc((size_t)NN * CAP * 4);    // padded CSR (12.8 MB)
    float*          alsA = (float*)alloc(NN * 4);
    float*          aldA = (float*)alloc(NN * 4);
    float*          alsB = (float*)alloc(NN * 4);
    float*          aldB = (float*)alloc(NN * 4);
    unsigned short* Wb   = (unsigned short*)alloc((size_t)3 * WL3 * 2);  // 3 forms x 3 layers
    float*          asf  = (float*)alloc(3 * HID * 4);
    float*          adf  = (float*)alloc(3 * HID * 4);
    float*          bff  = (float*)alloc(3 * HID * 4);
    unsigned short* xb0  = (unsigned short*)alloc((size_t)NN * HID * 2);  // x ping
    unsigned short* xb1  = (unsigned short*)alloc((size_t)NN * HID * 2);  // x pong

    // 1) prep: dtype + W forms + vectors + pos zero
    prep<<<197, 256, 0, stream>>>(z, Ws, as, ad, bb, Wb, asf, adf, bff, pos);

    // 2) gemm layer 0 (blocks first, no LDS) + de-replicated scatter (overlapped)
    scat_gemm0<<<GEMM_VB + SCAT_BLKS, 256, 0, stream>>>(z, ei, Wb, asf, adf,
                                                        pos, csrp, xb0, alsA, aldA);

    // 3) agg(layer0) + gemm(layer1): xb0 -> xb1, alsA -> alsB
    agg_gemm<<<AG_VB, 512, 0, stream>>>(xb0, pos, csrp, alsA, aldA, bff,
                                        Wb + WL3 + 2 * HH, Wb + WL3 + HH,
                                        asf + HID, adf + HID, xb1, alsB, aldB);

    // 4) agg(layer1) + gemm(layer2): xb1 -> xb0, alsB -> alsA
    agg_gemm<<<AG_VB, 512, 0, stream>>>(xb1, pos, csrp, alsB, aldB, bff + HID,
                                        Wb + 2 * WL3 + 2 * HH, Wb + 2 * WL3 + HH,
                                        asf + 2 * HID, adf + 2 * HID, xb0, alsA, aldA);

    // 5) final aggregate (layer2, no relu) -> d_out
    agg_fin<<<(NN + 3) / 4, 256, 0, stream>>>(z, xb0, pos, csrp, alsA, aldA,
                                              bff + 2 * HID, d_out);
}